// Round 1
// baseline (329.124 us; speedup 1.0000x reference)
//
#include <hip/hip_runtime.h>
#include <math.h>

#define HPIX 160
#define WPIX 160
#define NPIX 25600      // 160*160
#define C0   128
#define CM   64
#define MID  16
#define KK   11
#define KK2  121
#define PAD  5
#define BN_EPS 1e-5f

__device__ __forceinline__ float elu_f(float y) { return y > 0.f ? y : expm1f(y); }

// ---------------- Stage 1: out1 = elu(bn1(x)) ----------------
__global__ void k_bn1_elu(const float* __restrict__ x,
                          const float* __restrict__ g, const float* __restrict__ b,
                          const float* __restrict__ m, const float* __restrict__ v,
                          float* __restrict__ out) {
    int i = blockIdx.x * 256 + threadIdx.x;
    if (i >= C0 * NPIX) return;
    int c = i / NPIX;
    float inv = g[c] * rsqrtf(v[c] + BN_EPS);
    float y = x[i] * inv + (b[c] - m[c] * inv);
    out[i] = elu_f(y);
}

// ---------------- Generic conv1x1 (+ optional BN + act) ----------------
// out[c,p] = act(bn(sum_k w[c,k]*in[k,p]));  act: 0=elu, 1=relu, 2=none
__global__ void k_gemm(const float* __restrict__ in, const float* __restrict__ w,
                       const float* __restrict__ g, const float* __restrict__ b,
                       const float* __restrict__ m, const float* __restrict__ v,
                       float* __restrict__ out, int Kdim, int act) {
    int p = blockIdx.x * 256 + threadIdx.x;   // pixel
    int c = blockIdx.y;                        // output channel
    const float* wr = w + c * Kdim;
    float acc = 0.f;
    for (int k = 0; k < Kdim; ++k)
        acc = fmaf(wr[k], in[k * NPIX + p], acc);
    if (g) {
        float inv = g[c] * rsqrtf(v[c] + BN_EPS);
        acc = acc * inv + (b[c] - m[c] * inv);
    }
    if (act == 0)      acc = elu_f(acc);
    else if (act == 1) acc = fmaxf(acc, 0.f);
    out[c * NPIX + p] = acc;
}

// ---------------- Involution: fused wk-gen + patch weighted sum + bn3 + elu ----
// Block: 256 threads, 16 consecutive pixels (same image row since 160%16==0).
// Phase 1: stage t (16 mid-channels x 16 px) in LDS.
// Phase 2: wk[j][px] = inv_b2[j] + sum_m inv_w2[j,m]*t[m,px], j in [0,484).
// Phase 3: for each of 64 channels x 16 px: 11x11 weighted sum over feat, bn3+elu.
__global__ void k_involution(const float* __restrict__ t, const float* __restrict__ feat,
                             const float* __restrict__ inv_w2, const float* __restrict__ inv_b2,
                             const float* __restrict__ g3, const float* __restrict__ b3,
                             const float* __restrict__ m3, const float* __restrict__ v3,
                             float* __restrict__ out) {
    __shared__ float s_wk[484 * 16];   // [j][px]  ~31 KB
    __shared__ float s_t[MID][16];

    const int tid = threadIdx.x;
    const int p0  = blockIdx.x * 16;

    if (tid < MID * 16) {
        int mm = tid >> 4, px = tid & 15;
        s_t[mm][px] = t[mm * NPIX + p0 + px];
    }
    __syncthreads();

    for (int task = tid; task < 484 * 16; task += 256) {
        int j = task >> 4, px = task & 15;
        float acc = inv_b2[j];
        #pragma unroll
        for (int mm = 0; mm < MID; ++mm)
            acc = fmaf(inv_w2[j * MID + mm], s_t[mm][px], acc);
        s_wk[j * 16 + px] = acc;
    }
    __syncthreads();

    const int h  = p0 / WPIX;
    const int w0 = p0 % WPIX;

    for (int task = tid; task < CM * 16; task += 256) {
        int c  = task >> 4;
        int px = task & 15;
        int w  = w0 + px;
        int grp = c >> 4;
        float acc = 0.f;
        for (int kh = 0; kh < KK; ++kh) {
            int hh = h + kh - PAD;
            if (hh < 0 || hh >= HPIX) continue;
            const float* frow = feat + c * NPIX + hh * WPIX;
            const float* wkk  = s_wk + (grp * KK2 + kh * KK) * 16 + px;
            #pragma unroll
            for (int kw = 0; kw < KK; ++kw) {
                int ww = w + kw - PAD;
                if (ww < 0 || ww >= WPIX) continue;
                acc = fmaf(wkk[kw * 16], frow[ww], acc);
            }
        }
        float inv = g3[c] * rsqrtf(v3[c] + BN_EPS);
        float y = acc * inv + (b3[c] - m3[c] * inv);
        out[c * NPIX + p0 + px] = elu_f(y);
    }
}

// ---------------- SE: per-channel mean pool ----------------
__global__ void k_pool(const float* __restrict__ in, float* __restrict__ pooled) {
    int c = blockIdx.x;
    float s = 0.f;
    for (int p = threadIdx.x; p < NPIX; p += 256) s += in[c * NPIX + p];
    #pragma unroll
    for (int off = 32; off; off >>= 1) s += __shfl_down(s, off);
    __shared__ float sw[4];
    int lane = threadIdx.x & 63, wid = threadIdx.x >> 6;
    if (lane == 0) sw[wid] = s;
    __syncthreads();
    if (threadIdx.x == 0)
        pooled[c] = (sw[0] + sw[1] + sw[2] + sw[3]) * (1.f / NPIX);
}

// ---------------- SE: 128->8 relu -> 8->128 sigmoid ----------------
__global__ void k_se(const float* __restrict__ pooled,
                     const float* __restrict__ w1, const float* __restrict__ b1,
                     const float* __restrict__ w2, const float* __restrict__ b2,
                     float* __restrict__ scale) {
    __shared__ float s_p[C0];
    __shared__ float s_h[8];
    int tid = threadIdx.x;
    s_p[tid] = pooled[tid];
    __syncthreads();
    if (tid < 8) {
        float acc = b1[tid];
        for (int c = 0; c < C0; ++c) acc = fmaf(w1[tid * C0 + c], s_p[c], acc);
        s_h[tid] = fmaxf(acc, 0.f);
    }
    __syncthreads();
    float acc = b2[tid];
    #pragma unroll
    for (int j = 0; j < 8; ++j) acc = fmaf(w2[tid * 8 + j], s_h[j], acc);
    scale[tid] = 1.f / (1.f + expf(-acc));
}

// ---------------- Final: out = pre * scale[c] + x ----------------
__global__ void k_final(const float* __restrict__ pre, const float* __restrict__ scale,
                        const float* __restrict__ x, float* __restrict__ out) {
    int i = blockIdx.x * 256 + threadIdx.x;
    if (i >= C0 * NPIX) return;
    int c = i / NPIX;
    out[i] = fmaf(pre[i], scale[c], x[i]);
}

extern "C" void kernel_launch(void* const* d_in, const int* in_sizes, int n_in,
                              void* d_out, int out_size, void* d_ws, size_t ws_size,
                              hipStream_t stream) {
    const float* x      = (const float*)d_in[0];
    const float* g1     = (const float*)d_in[1];
    const float* b1     = (const float*)d_in[2];
    const float* m1     = (const float*)d_in[3];
    const float* v1     = (const float*)d_in[4];
    const float* w1     = (const float*)d_in[5];
    const float* g2     = (const float*)d_in[6];
    const float* b2     = (const float*)d_in[7];
    const float* m2     = (const float*)d_in[8];
    const float* v2     = (const float*)d_in[9];
    const float* inv_w1 = (const float*)d_in[10];
    const float* ig     = (const float*)d_in[11];
    const float* ib     = (const float*)d_in[12];
    const float* im     = (const float*)d_in[13];
    const float* iv     = (const float*)d_in[14];
    const float* inv_w2 = (const float*)d_in[15];
    const float* inv_b2 = (const float*)d_in[16];
    const float* g3     = (const float*)d_in[17];
    const float* b3     = (const float*)d_in[18];
    const float* m3     = (const float*)d_in[19];
    const float* v3     = (const float*)d_in[20];
    const float* w3     = (const float*)d_in[21];
    const float* se_w1  = (const float*)d_in[22];
    const float* se_b1  = (const float*)d_in[23];
    const float* se_w2  = (const float*)d_in[24];
    const float* se_b2  = (const float*)d_in[25];
    float* out = (float*)d_out;

    float* ws   = (float*)d_ws;
    float* buf1 = ws;                       // elu(bn1(x)):      128*25600
    float* buf2 = buf1 + C0 * NPIX;         // elu(bn2(conv1)):   64*25600
    float* buf3 = buf2 + CM * NPIX;         // t:                 16*25600
    float* buf5 = buf3 + MID * NPIX;        // elu(bn3(invol)):   64*25600
    float* buf6 = buf5 + CM * NPIX;         // conv3 out:        128*25600
    float* pooled = buf6 + C0 * NPIX;       // 128
    float* scale  = pooled + C0;            // 128

    // 1. bn1 + elu
    k_bn1_elu<<<(C0 * NPIX + 255) / 256, 256, 0, stream>>>(x, g1, b1, m1, v1, buf1);

    // 2. conv1x1 128->64 + bn2 + elu
    k_gemm<<<dim3(NPIX / 256, CM), 256, 0, stream>>>(buf1, w1, g2, b2, m2, v2, buf2, C0, 0);

    // 3a. involution reduce: conv1x1 64->16 + bn + relu
    k_gemm<<<dim3(NPIX / 256, MID), 256, 0, stream>>>(buf2, inv_w1, ig, ib, im, iv, buf3, CM, 1);

    // 3b. involution (wk-gen fused with patch weighted sum) + bn3 + elu
    k_involution<<<NPIX / 16, 256, 0, stream>>>(buf3, buf2, inv_w2, inv_b2,
                                                g3, b3, m3, v3, buf5);

    // 4. conv1x1 64->128 (no bn/act)
    k_gemm<<<dim3(NPIX / 256, C0), 256, 0, stream>>>(buf5, w3, nullptr, nullptr, nullptr, nullptr,
                                                     buf6, CM, 2);

    // 5. SE
    k_pool<<<C0, 256, 0, stream>>>(buf6, pooled);
    k_se<<<1, C0, 0, stream>>>(pooled, se_w1, se_b1, se_w2, se_b2, scale);

    // 6. out = buf6 * scale + x
    k_final<<<(C0 * NPIX + 255) / 256, 256, 0, stream>>>(buf6, scale, x, out);
}

// Round 2
// 189.090 us; speedup vs baseline: 1.7406x; 1.7406x over previous
//
#include <hip/hip_runtime.h>
#include <math.h>

#define HPIX 160
#define WPIX 160
#define NPIX 25600      // 160*160
#define C0   128
#define CM   64
#define MID  16
#define KK   11
#define KK2  121
#define PAD  5
#define PADW 176        // 160 + 2*5, rounded up to 16 for row alignment
#define PADH 170
#define CHP  (PADH*PADW)   // 29920 floats per padded channel
#define BN_EPS 1e-5f

__device__ __forceinline__ float elu_f(float y) { return y > 0.f ? y : expm1f(y); }

// ---------------- conv1: x -> elu(bn2(w1 @ elu(bn1(x)))) into padded feat ----
// grid (NPIX/256, CM/8), block 256. Each thread: 1 pixel, 8 output channels.
__global__ __launch_bounds__(256) void k_conv1(
        const float* __restrict__ x, const float* __restrict__ w1,
        const float* __restrict__ g1, const float* __restrict__ b1,
        const float* __restrict__ m1, const float* __restrict__ v1,
        const float* __restrict__ g2, const float* __restrict__ b2,
        const float* __restrict__ m2, const float* __restrict__ v2,
        float* __restrict__ feat_pad) {
    __shared__ float s_inv1[C0], s_beta1[C0];
    const int tid = threadIdx.x;
    if (tid < C0) {
        float inv = g1[tid] * rsqrtf(v1[tid] + BN_EPS);
        s_inv1[tid]  = inv;
        s_beta1[tid] = b1[tid] - m1[tid] * inv;
    }
    __syncthreads();

    const int p   = blockIdx.x * 256 + tid;
    const int oc0 = blockIdx.y * 8;
    const float* wbase = w1 + oc0 * C0;

    float acc[8] = {0,0,0,0,0,0,0,0};
    #pragma unroll 4
    for (int k = 0; k < C0; ++k) {
        float a = fmaf(x[k * NPIX + p], s_inv1[k], s_beta1[k]);
        a = elu_f(a);
        #pragma unroll
        for (int j = 0; j < 8; ++j)
            acc[j] = fmaf(wbase[j * C0 + k], a, acc[j]);
    }

    const int h = p / WPIX, w = p % WPIX;
    const int off = (h + PAD) * PADW + (w + PAD);
    #pragma unroll
    for (int j = 0; j < 8; ++j) {
        int c = oc0 + j;
        float inv = g2[c] * rsqrtf(v2[c] + BN_EPS);
        float y = acc[j] * inv + (b2[c] - m2[c] * inv);
        feat_pad[c * CHP + off] = elu_f(y);
    }
}

// ---------------- conv_t: feat_pad -> t = relu(bn(inv_w1 @ feat)) -----------
// grid (NPIX/256, MID/8), block 256.
__global__ __launch_bounds__(256) void k_conv_t(
        const float* __restrict__ feat_pad, const float* __restrict__ wt,
        const float* __restrict__ g, const float* __restrict__ b,
        const float* __restrict__ m, const float* __restrict__ v,
        float* __restrict__ t) {
    const int tid = threadIdx.x;
    const int p   = blockIdx.x * 256 + tid;
    const int oc0 = blockIdx.y * 8;
    const int h = p / WPIX, w = p % WPIX;
    const int off = (h + PAD) * PADW + (w + PAD);
    const float* wbase = wt + oc0 * CM;

    float acc[8] = {0,0,0,0,0,0,0,0};
    #pragma unroll 4
    for (int k = 0; k < CM; ++k) {
        float a = feat_pad[k * CHP + off];
        #pragma unroll
        for (int j = 0; j < 8; ++j)
            acc[j] = fmaf(wbase[j * CM + k], a, acc[j]);
    }
    #pragma unroll
    for (int j = 0; j < 8; ++j) {
        int c = oc0 + j;
        float inv = g[c] * rsqrtf(v[c] + BN_EPS);
        float y = acc[j] * inv + (b[c] - m[c] * inv);
        t[c * NPIX + p] = fmaxf(y, 0.f);
    }
}

// ---------------- involution: wk-gen + 11x11 weighted sum + bn3 + elu -------
// Block 256 = 16 px (one row segment) x 16 "channel quads".
__global__ __launch_bounds__(256) void k_involution(
        const float* __restrict__ t, const float* __restrict__ feat_pad,
        const float* __restrict__ inv_w2, const float* __restrict__ inv_b2,
        const float* __restrict__ g3, const float* __restrict__ b3,
        const float* __restrict__ m3, const float* __restrict__ v3,
        float* __restrict__ out) {
    __shared__ float s_wk[484 * 16];   // [j][px], ~31 KB
    __shared__ float s_t[MID * 16];

    const int tid = threadIdx.x;
    const int p0  = blockIdx.x * 16;   // 16 consecutive px, same image row
    const int px  = tid & 15;
    const int c4  = tid >> 4;          // 0..15

    s_t[tid] = t[c4 * NPIX + p0 + px]; // c4 doubles as mid-channel index here
    __syncthreads();

    // phase 2: wk[j][px] for this px; j strided by 16 across c4
    float tr[MID];
    #pragma unroll
    for (int mm = 0; mm < MID; ++mm) tr[mm] = s_t[mm * 16 + px];
    for (int j = c4; j < 484; j += 16) {
        const float4* wrow = (const float4*)(inv_w2 + j * MID);
        float acc = inv_b2[j];
        #pragma unroll
        for (int q = 0; q < 4; ++q) {
            float4 wv = wrow[q];
            acc = fmaf(wv.x, tr[q*4+0], acc);
            acc = fmaf(wv.y, tr[q*4+1], acc);
            acc = fmaf(wv.z, tr[q*4+2], acc);
            acc = fmaf(wv.w, tr[q*4+3], acc);
        }
        s_wk[j * 16 + px] = acc;
    }
    __syncthreads();

    // phase 3: 4 channels per thread (same group), 4 independent acc chains
    const int h  = p0 / WPIX;
    const int w0 = p0 % WPIX;
    const int c_base = c4 * 4;
    const int g = c_base >> 4;
    const float* wkbase = s_wk + g * KK2 * 16 + px;
    const float* f0 = feat_pad + c_base * CHP + h * PADW + (w0 + px);

    float acc0 = 0.f, acc1 = 0.f, acc2 = 0.f, acc3 = 0.f;
    #pragma unroll
    for (int kh = 0; kh < KK; ++kh) {
        const float* fr  = f0 + kh * PADW;
        const float* wkk = wkbase + kh * KK * 16;
        #pragma unroll
        for (int kw = 0; kw < KK; ++kw) {
            float wv = wkk[kw * 16];
            acc0 = fmaf(wv, fr[0 * CHP + kw], acc0);
            acc1 = fmaf(wv, fr[1 * CHP + kw], acc1);
            acc2 = fmaf(wv, fr[2 * CHP + kw], acc2);
            acc3 = fmaf(wv, fr[3 * CHP + kw], acc3);
        }
    }

    float accs[4] = {acc0, acc1, acc2, acc3};
    #pragma unroll
    for (int j = 0; j < 4; ++j) {
        int c = c_base + j;
        float inv = g3[c] * rsqrtf(v3[c] + BN_EPS);
        float y = accs[j] * inv + (b3[c] - m3[c] * inv);
        out[c * NPIX + p0 + px] = elu_f(y);
    }
}

// ---------------- conv3: buf5 -> buf6 (64 -> 128, no bn/act) ----------------
__global__ __launch_bounds__(256) void k_conv3(
        const float* __restrict__ in, const float* __restrict__ w,
        float* __restrict__ out) {
    const int tid = threadIdx.x;
    const int p   = blockIdx.x * 256 + tid;
    const int oc0 = blockIdx.y * 8;
    const float* wbase = w + oc0 * CM;

    float acc[8] = {0,0,0,0,0,0,0,0};
    #pragma unroll 4
    for (int k = 0; k < CM; ++k) {
        float a = in[k * NPIX + p];
        #pragma unroll
        for (int j = 0; j < 8; ++j)
            acc[j] = fmaf(wbase[j * CM + k], a, acc[j]);
    }
    #pragma unroll
    for (int j = 0; j < 8; ++j)
        out[(oc0 + j) * NPIX + p] = acc[j];
}

// ---------------- SE: per-channel mean pool ----------------
__global__ void k_pool(const float* __restrict__ in, float* __restrict__ pooled) {
    int c = blockIdx.x;
    float s = 0.f;
    for (int p = threadIdx.x; p < NPIX; p += 256) s += in[c * NPIX + p];
    #pragma unroll
    for (int off = 32; off; off >>= 1) s += __shfl_down(s, off);
    __shared__ float sw[4];
    int lane = threadIdx.x & 63, wid = threadIdx.x >> 6;
    if (lane == 0) sw[wid] = s;
    __syncthreads();
    if (threadIdx.x == 0)
        pooled[c] = (sw[0] + sw[1] + sw[2] + sw[3]) * (1.f / NPIX);
}

// ---------------- SE MLP: 128->8 relu -> 8->128 sigmoid ----------------
__global__ void k_se(const float* __restrict__ pooled,
                     const float* __restrict__ w1, const float* __restrict__ b1,
                     const float* __restrict__ w2, const float* __restrict__ b2,
                     float* __restrict__ scale) {
    __shared__ float s_p[C0];
    __shared__ float s_h[8];
    int tid = threadIdx.x;
    s_p[tid] = pooled[tid];
    __syncthreads();
    if (tid < 8) {
        float acc = b1[tid];
        for (int c = 0; c < C0; ++c) acc = fmaf(w1[tid * C0 + c], s_p[c], acc);
        s_h[tid] = fmaxf(acc, 0.f);
    }
    __syncthreads();
    float acc = b2[tid];
    #pragma unroll
    for (int j = 0; j < 8; ++j) acc = fmaf(w2[tid * 8 + j], s_h[j], acc);
    scale[tid] = 1.f / (1.f + expf(-acc));
}

// ---------------- Final: out = pre * scale[c] + x ----------------
__global__ void k_final(const float* __restrict__ pre, const float* __restrict__ scale,
                        const float* __restrict__ x, float* __restrict__ out) {
    int i = blockIdx.x * 256 + threadIdx.x;
    int c = i / NPIX;
    out[i] = fmaf(pre[i], scale[c], x[i]);
}

extern "C" void kernel_launch(void* const* d_in, const int* in_sizes, int n_in,
                              void* d_out, int out_size, void* d_ws, size_t ws_size,
                              hipStream_t stream) {
    const float* x      = (const float*)d_in[0];
    const float* g1     = (const float*)d_in[1];
    const float* b1     = (const float*)d_in[2];
    const float* m1     = (const float*)d_in[3];
    const float* v1     = (const float*)d_in[4];
    const float* w1     = (const float*)d_in[5];
    const float* g2     = (const float*)d_in[6];
    const float* b2     = (const float*)d_in[7];
    const float* m2     = (const float*)d_in[8];
    const float* v2     = (const float*)d_in[9];
    const float* inv_w1 = (const float*)d_in[10];
    const float* ig     = (const float*)d_in[11];
    const float* ib     = (const float*)d_in[12];
    const float* im     = (const float*)d_in[13];
    const float* iv     = (const float*)d_in[14];
    const float* inv_w2 = (const float*)d_in[15];
    const float* inv_b2 = (const float*)d_in[16];
    const float* g3     = (const float*)d_in[17];
    const float* b3     = (const float*)d_in[18];
    const float* m3     = (const float*)d_in[19];
    const float* v3     = (const float*)d_in[20];
    const float* w3     = (const float*)d_in[21];
    const float* se_w1  = (const float*)d_in[22];
    const float* se_b1  = (const float*)d_in[23];
    const float* se_w2  = (const float*)d_in[24];
    const float* se_b2  = (const float*)d_in[25];
    float* out = (float*)d_out;

    float* ws       = (float*)d_ws;
    float* feat_pad = ws;                        // 64 * 29920 (zero-padded)
    float* buf_t    = feat_pad + CM * CHP;       // 16 * 25600
    float* buf5     = buf_t + MID * NPIX;        // 64 * 25600
    float* buf6     = buf5 + CM * NPIX;          // 128 * 25600
    float* pooled   = buf6 + C0 * NPIX;          // 128
    float* scale    = pooled + C0;               // 128

    // zero padded feat (border must be 0 every call)
    hipMemsetAsync(feat_pad, 0, (size_t)CM * CHP * sizeof(float), stream);

    // 1+2. fused bn1+elu + conv1x1 128->64 + bn2+elu, into padded layout
    k_conv1<<<dim3(NPIX / 256, CM / 8), 256, 0, stream>>>(
        x, w1, g1, b1, m1, v1, g2, b2, m2, v2, feat_pad);

    // 3a. involution reduce: conv1x1 64->16 + bn + relu
    k_conv_t<<<dim3(NPIX / 256, MID / 8), 256, 0, stream>>>(
        feat_pad, inv_w1, ig, ib, im, iv, buf_t);

    // 3b. involution (wk-gen + weighted patch sum) + bn3 + elu
    k_involution<<<NPIX / 16, 256, 0, stream>>>(buf_t, feat_pad, inv_w2, inv_b2,
                                                g3, b3, m3, v3, buf5);

    // 4. conv1x1 64->128
    k_conv3<<<dim3(NPIX / 256, C0 / 8), 256, 0, stream>>>(buf5, w3, buf6);

    // 5. SE
    k_pool<<<C0, 256, 0, stream>>>(buf6, pooled);
    k_se<<<1, C0, 0, stream>>>(pooled, se_w1, se_b1, se_w2, se_b2, scale);

    // 6. out = buf6 * scale + x
    k_final<<<(C0 * NPIX) / 256, 256, 0, stream>>>(buf6, scale, x, out);
}

// Round 3
// 169.158 us; speedup vs baseline: 1.9457x; 1.1178x over previous
//
#include <hip/hip_runtime.h>
#include <math.h>

#define HPIX 160
#define WPIX 160
#define NPIX 25600      // 160*160
#define C0   128
#define CM   64
#define MID  16
#define KK   11
#define KK2  121
#define PAD  5
#define PADW 176        // 160 + 2*5, rounded up to 16 for row alignment
#define PADH 170
#define CHP  (PADH*PADW)   // 29920 floats per padded channel
#define BN_EPS 1e-5f

__device__ __forceinline__ float elu_f(float y) { return y > 0.f ? y : expm1f(y); }

// ---------------- conv1: x -> elu(bn2(w1 @ elu(bn1(x)))) into padded feat ----
// grid (NPIX/256, CM/8), block 256. Each thread: 1 pixel, 8 output channels.
__global__ __launch_bounds__(256, 4) void k_conv1(
        const float* __restrict__ x, const float* __restrict__ w1,
        const float* __restrict__ g1, const float* __restrict__ b1,
        const float* __restrict__ m1, const float* __restrict__ v1,
        const float* __restrict__ g2, const float* __restrict__ b2,
        const float* __restrict__ m2, const float* __restrict__ v2,
        float* __restrict__ feat_pad) {
    __shared__ float s_inv1[C0], s_beta1[C0];
    const int tid = threadIdx.x;
    if (tid < C0) {
        float inv = g1[tid] * rsqrtf(v1[tid] + BN_EPS);
        s_inv1[tid]  = inv;
        s_beta1[tid] = b1[tid] - m1[tid] * inv;
    }
    __syncthreads();

    const int p   = blockIdx.x * 256 + tid;
    const int oc0 = blockIdx.y * 8;
    const float* wbase = w1 + oc0 * C0;

    float acc[8] = {0,0,0,0,0,0,0,0};
    #pragma unroll 4
    for (int k = 0; k < C0; ++k) {
        float a = fmaf(x[k * NPIX + p], s_inv1[k], s_beta1[k]);
        a = elu_f(a);
        #pragma unroll
        for (int j = 0; j < 8; ++j)
            acc[j] = fmaf(wbase[j * C0 + k], a, acc[j]);
    }

    const int h = p / WPIX, w = p % WPIX;
    const int off = (h + PAD) * PADW + (w + PAD);
    #pragma unroll
    for (int j = 0; j < 8; ++j) {
        int c = oc0 + j;
        float inv = g2[c] * rsqrtf(v2[c] + BN_EPS);
        float y = acc[j] * inv + (b2[c] - m2[c] * inv);
        feat_pad[c * CHP + off] = elu_f(y);
    }
}

// ---------------- conv_t: feat_pad -> t = relu(bn(inv_w1 @ feat)) -----------
// grid (NPIX/256, MID/8), block 256.
__global__ __launch_bounds__(256, 4) void k_conv_t(
        const float* __restrict__ feat_pad, const float* __restrict__ wt,
        const float* __restrict__ g, const float* __restrict__ b,
        const float* __restrict__ m, const float* __restrict__ v,
        float* __restrict__ t) {
    const int tid = threadIdx.x;
    const int p   = blockIdx.x * 256 + tid;
    const int oc0 = blockIdx.y * 8;
    const int h = p / WPIX, w = p % WPIX;
    const int off = (h + PAD) * PADW + (w + PAD);
    const float* wbase = wt + oc0 * CM;

    float acc[8] = {0,0,0,0,0,0,0,0};
    #pragma unroll 4
    for (int k = 0; k < CM; ++k) {
        float a = feat_pad[k * CHP + off];
        #pragma unroll
        for (int j = 0; j < 8; ++j)
            acc[j] = fmaf(wbase[j * CM + k], a, acc[j]);
    }
    #pragma unroll
    for (int j = 0; j < 8; ++j) {
        int c = oc0 + j;
        float inv = g[c] * rsqrtf(v[c] + BN_EPS);
        float y = acc[j] * inv + (b[c] - m[c] * inv);
        t[c * NPIX + p] = fmaxf(y, 0.f);
    }
}

// ---------------- involution: wk-gen + 11x11 weighted sum + bn3 + elu -------
// Block 256 = 16 px (one row segment) x 16 "channel quads".
__global__ __launch_bounds__(256, 4) void k_involution(
        const float* __restrict__ t, const float* __restrict__ feat_pad,
        const float* __restrict__ inv_w2, const float* __restrict__ inv_b2,
        const float* __restrict__ g3, const float* __restrict__ b3,
        const float* __restrict__ m3, const float* __restrict__ v3,
        float* __restrict__ out) {
    __shared__ float s_wk[484 * 16];   // [j][px], ~31 KB
    __shared__ float s_t[MID * 16];

    const int tid = threadIdx.x;
    const int p0  = blockIdx.x * 16;   // 16 consecutive px, same image row
    const int px  = tid & 15;
    const int c4  = tid >> 4;          // 0..15

    s_t[tid] = t[c4 * NPIX + p0 + px]; // c4 doubles as mid-channel index here
    __syncthreads();

    // phase 2: wk[j][px] for this px; j strided by 16 across c4
    float tr[MID];
    #pragma unroll
    for (int mm = 0; mm < MID; ++mm) tr[mm] = s_t[mm * 16 + px];
    for (int j = c4; j < 484; j += 16) {
        const float4* wrow = (const float4*)(inv_w2 + j * MID);
        float acc = inv_b2[j];
        #pragma unroll
        for (int q = 0; q < 4; ++q) {
            float4 wv = wrow[q];
            acc = fmaf(wv.x, tr[q*4+0], acc);
            acc = fmaf(wv.y, tr[q*4+1], acc);
            acc = fmaf(wv.z, tr[q*4+2], acc);
            acc = fmaf(wv.w, tr[q*4+3], acc);
        }
        s_wk[j * 16 + px] = acc;
    }
    __syncthreads();

    // phase 3: 4 channels per thread (same group), 4 independent acc chains.
    // NOTE: kh loop deliberately NOT fully unrolled — full unroll blew VGPRs
    // to 256 (occupancy 10%). unroll 2 + launch_bounds(256,4) keeps <=128.
    const int h  = p0 / WPIX;
    const int w0 = p0 % WPIX;
    const int c_base = c4 * 4;
    const int g = c_base >> 4;
    const float* wkbase = s_wk + g * KK2 * 16 + px;
    const float* f0 = feat_pad + c_base * CHP + h * PADW + (w0 + px);

    float acc0 = 0.f, acc1 = 0.f, acc2 = 0.f, acc3 = 0.f;
    #pragma unroll 2
    for (int kh = 0; kh < KK; ++kh) {
        const float* fr  = f0 + kh * PADW;
        const float* wkk = wkbase + kh * KK * 16;
        #pragma unroll
        for (int kw = 0; kw < KK; ++kw) {
            float wv = wkk[kw * 16];
            acc0 = fmaf(wv, fr[0 * CHP + kw], acc0);
            acc1 = fmaf(wv, fr[1 * CHP + kw], acc1);
            acc2 = fmaf(wv, fr[2 * CHP + kw], acc2);
            acc3 = fmaf(wv, fr[3 * CHP + kw], acc3);
        }
    }

    // bn3 constants hoisted: 4 channels
    float accs[4] = {acc0, acc1, acc2, acc3};
    #pragma unroll
    for (int j = 0; j < 4; ++j) {
        int c = c_base + j;
        float inv = g3[c] * rsqrtf(v3[c] + BN_EPS);
        float y = accs[j] * inv + (b3[c] - m3[c] * inv);
        out[c * NPIX + p0 + px] = elu_f(y);
    }
}

// ---------------- conv3: buf5 -> buf6 (64 -> 128, no bn/act) ----------------
__global__ __launch_bounds__(256, 4) void k_conv3(
        const float* __restrict__ in, const float* __restrict__ w,
        float* __restrict__ out) {
    const int tid = threadIdx.x;
    const int p   = blockIdx.x * 256 + tid;
    const int oc0 = blockIdx.y * 8;
    const float* wbase = w + oc0 * CM;

    float acc[8] = {0,0,0,0,0,0,0,0};
    #pragma unroll 4
    for (int k = 0; k < CM; ++k) {
        float a = in[k * NPIX + p];
        #pragma unroll
        for (int j = 0; j < 8; ++j)
            acc[j] = fmaf(wbase[j * CM + k], a, acc[j]);
    }
    #pragma unroll
    for (int j = 0; j < 8; ++j)
        out[(oc0 + j) * NPIX + p] = acc[j];
}

// ---------------- SE: per-channel mean pool ----------------
__global__ void k_pool(const float* __restrict__ in, float* __restrict__ pooled) {
    int c = blockIdx.x;
    float s = 0.f;
    for (int p = threadIdx.x; p < NPIX; p += 256) s += in[c * NPIX + p];
    #pragma unroll
    for (int off = 32; off; off >>= 1) s += __shfl_down(s, off);
    __shared__ float sw[4];
    int lane = threadIdx.x & 63, wid = threadIdx.x >> 6;
    if (lane == 0) sw[wid] = s;
    __syncthreads();
    if (threadIdx.x == 0)
        pooled[c] = (sw[0] + sw[1] + sw[2] + sw[3]) * (1.f / NPIX);
}

// ---------------- SE MLP: 128->8 relu -> 8->128 sigmoid ----------------
__global__ void k_se(const float* __restrict__ pooled,
                     const float* __restrict__ w1, const float* __restrict__ b1,
                     const float* __restrict__ w2, const float* __restrict__ b2,
                     float* __restrict__ scale) {
    __shared__ float s_p[C0];
    __shared__ float s_h[8];
    int tid = threadIdx.x;
    s_p[tid] = pooled[tid];
    __syncthreads();
    if (tid < 8) {
        float acc = b1[tid];
        for (int c = 0; c < C0; ++c) acc = fmaf(w1[tid * C0 + c], s_p[c], acc);
        s_h[tid] = fmaxf(acc, 0.f);
    }
    __syncthreads();
    float acc = b2[tid];
    #pragma unroll
    for (int j = 0; j < 8; ++j) acc = fmaf(w2[tid * 8 + j], s_h[j], acc);
    scale[tid] = 1.f / (1.f + expf(-acc));
}

// ---------------- Final: out = pre * scale[c] + x ----------------
__global__ void k_final(const float* __restrict__ pre, const float* __restrict__ scale,
                        const float* __restrict__ x, float* __restrict__ out) {
    int i = blockIdx.x * 256 + threadIdx.x;
    int c = i / NPIX;
    out[i] = fmaf(pre[i], scale[c], x[i]);
}

extern "C" void kernel_launch(void* const* d_in, const int* in_sizes, int n_in,
                              void* d_out, int out_size, void* d_ws, size_t ws_size,
                              hipStream_t stream) {
    const float* x      = (const float*)d_in[0];
    const float* g1     = (const float*)d_in[1];
    const float* b1     = (const float*)d_in[2];
    const float* m1     = (const float*)d_in[3];
    const float* v1     = (const float*)d_in[4];
    const float* w1     = (const float*)d_in[5];
    const float* g2     = (const float*)d_in[6];
    const float* b2     = (const float*)d_in[7];
    const float* m2     = (const float*)d_in[8];
    const float* v2     = (const float*)d_in[9];
    const float* inv_w1 = (const float*)d_in[10];
    const float* ig     = (const float*)d_in[11];
    const float* ib     = (const float*)d_in[12];
    const float* im     = (const float*)d_in[13];
    const float* iv     = (const float*)d_in[14];
    const float* inv_w2 = (const float*)d_in[15];
    const float* inv_b2 = (const float*)d_in[16];
    const float* g3     = (const float*)d_in[17];
    const float* b3     = (const float*)d_in[18];
    const float* m3     = (const float*)d_in[19];
    const float* v3     = (const float*)d_in[20];
    const float* w3     = (const float*)d_in[21];
    const float* se_w1  = (const float*)d_in[22];
    const float* se_b1  = (const float*)d_in[23];
    const float* se_w2  = (const float*)d_in[24];
    const float* se_b2  = (const float*)d_in[25];
    float* out = (float*)d_out;

    float* ws       = (float*)d_ws;
    float* feat_pad = ws;                        // 64 * 29920 (zero-padded)
    float* buf_t    = feat_pad + CM * CHP;       // 16 * 25600
    float* buf5     = buf_t + MID * NPIX;        // 64 * 25600
    float* buf6     = buf5 + CM * NPIX;          // 128 * 25600
    float* pooled   = buf6 + C0 * NPIX;          // 128
    float* scale    = pooled + C0;               // 128

    // zero padded feat (border must be 0 every call)
    hipMemsetAsync(feat_pad, 0, (size_t)CM * CHP * sizeof(float), stream);

    // 1+2. fused bn1+elu + conv1x1 128->64 + bn2+elu, into padded layout
    k_conv1<<<dim3(NPIX / 256, CM / 8), 256, 0, stream>>>(
        x, w1, g1, b1, m1, v1, g2, b2, m2, v2, feat_pad);

    // 3a. involution reduce: conv1x1 64->16 + bn + relu
    k_conv_t<<<dim3(NPIX / 256, MID / 8), 256, 0, stream>>>(
        feat_pad, inv_w1, ig, ib, im, iv, buf_t);

    // 3b. involution (wk-gen + weighted patch sum) + bn3 + elu
    k_involution<<<NPIX / 16, 256, 0, stream>>>(buf_t, feat_pad, inv_w2, inv_b2,
                                                g3, b3, m3, v3, buf5);

    // 4. conv1x1 64->128
    k_conv3<<<dim3(NPIX / 256, C0 / 8), 256, 0, stream>>>(buf5, w3, buf6);

    // 5. SE
    k_pool<<<C0, 256, 0, stream>>>(buf6, pooled);
    k_se<<<1, C0, 0, stream>>>(pooled, se_w1, se_b1, se_w2, se_b2, scale);

    // 6. out = buf6 * scale + x
    k_final<<<(C0 * NPIX) / 256, 256, 0, stream>>>(buf6, scale, x, out);
}

// Round 4
// 119.582 us; speedup vs baseline: 2.7523x; 1.4146x over previous
//
#include <hip/hip_runtime.h>
#include <math.h>

#define HPIX 160
#define WPIX 160
#define NPIX 25600      // 160*160
#define C0   128
#define CM   64
#define MID  16
#define KK   11
#define KK2  121
#define PAD  5
#define PADW 176        // 160 + 2*5, rounded up to 16 for row alignment
#define PADH 170
#define CHP  (PADH*PADW)   // 29920 floats per padded channel
#define BN_EPS 1e-5f

__device__ __forceinline__ float elu_f(float y) { return y > 0.f ? y : expm1f(y); }

// ---------------- act = elu(bn1(x)), vectorized float4 ----------------
__global__ __launch_bounds__(256) void k_act(
        const float* __restrict__ x,
        const float* __restrict__ g1, const float* __restrict__ b1,
        const float* __restrict__ m1, const float* __restrict__ v1,
        float* __restrict__ act) {
    int i4 = blockIdx.x * 256 + threadIdx.x;   // 819200 float4s, grid 3200
    int c = i4 / (NPIX / 4);
    float inv  = g1[c] * rsqrtf(v1[c] + BN_EPS);
    float beta = b1[c] - m1[c] * inv;
    float4 xv = ((const float4*)x)[i4];
    float4 o;
    o.x = elu_f(fmaf(xv.x, inv, beta));
    o.y = elu_f(fmaf(xv.y, inv, beta));
    o.z = elu_f(fmaf(xv.z, inv, beta));
    o.w = elu_f(fmaf(xv.w, inv, beta));
    ((float4*)act)[i4] = o;
}

// ---------------- conv1: act -> elu(bn2(w1 @ act)) into padded feat ----
// grid (NPIX/256, CM/8), block 256. Thread: 1 pixel, 8 output channels.
__global__ __launch_bounds__(256, 4) void k_conv1(
        const float* __restrict__ act, const float* __restrict__ w1,
        const float* __restrict__ g2, const float* __restrict__ b2,
        const float* __restrict__ m2, const float* __restrict__ v2,
        float* __restrict__ feat_pad) {
    const int tid = threadIdx.x;
    const int p   = blockIdx.x * 256 + tid;
    const int oc0 = blockIdx.y * 8;
    const float* wbase = w1 + oc0 * C0;

    float acc[8] = {0,0,0,0,0,0,0,0};
    #pragma unroll 4
    for (int k = 0; k < C0; ++k) {
        float a = act[k * NPIX + p];
        #pragma unroll
        for (int j = 0; j < 8; ++j)
            acc[j] = fmaf(wbase[j * C0 + k], a, acc[j]);
    }

    const int h = p / WPIX, w = p % WPIX;
    const int off = (h + PAD) * PADW + (w + PAD);
    #pragma unroll
    for (int j = 0; j < 8; ++j) {
        int c = oc0 + j;
        float inv = g2[c] * rsqrtf(v2[c] + BN_EPS);
        float y = acc[j] * inv + (b2[c] - m2[c] * inv);
        feat_pad[c * CHP + off] = elu_f(y);
    }
}

// ---------------- conv_t: feat_pad -> t = relu(bn(inv_w1 @ feat)) -----------
// grid (NPIX/256, MID/2), block 256. Thread: 1 pixel, 2 output channels.
__global__ __launch_bounds__(256, 4) void k_conv_t(
        const float* __restrict__ feat_pad, const float* __restrict__ wt,
        const float* __restrict__ g, const float* __restrict__ b,
        const float* __restrict__ m, const float* __restrict__ v,
        float* __restrict__ t) {
    const int tid = threadIdx.x;
    const int p   = blockIdx.x * 256 + tid;
    const int oc0 = blockIdx.y * 2;
    const int h = p / WPIX, w = p % WPIX;
    const int off = (h + PAD) * PADW + (w + PAD);

    float acc0 = 0.f, acc1 = 0.f;
    #pragma unroll 8
    for (int k = 0; k < CM; ++k) {
        float a = feat_pad[k * CHP + off];
        acc0 = fmaf(wt[oc0 * CM + k], a, acc0);
        acc1 = fmaf(wt[(oc0 + 1) * CM + k], a, acc1);
    }
    {
        float inv = g[oc0] * rsqrtf(v[oc0] + BN_EPS);
        t[oc0 * NPIX + p] = fmaxf(acc0 * inv + (b[oc0] - m[oc0] * inv), 0.f);
    }
    {
        int c = oc0 + 1;
        float inv = g[c] * rsqrtf(v[c] + BN_EPS);
        t[c * NPIX + p] = fmaxf(acc1 * inv + (b[c] - m[c] * inv), 0.f);
    }
}

// ---------------- involution: wk-gen + 11x11 weighted sum + bn3 + elu -------
// Block 256, covers 16 consecutive px (one row) x 64 channels.
// Phase 3: thread = 4 px x 1 channel, register sliding window over kw.
__global__ __launch_bounds__(256, 4) void k_involution(
        const float* __restrict__ t, const float* __restrict__ feat_pad,
        const float* __restrict__ inv_w2, const float* __restrict__ inv_b2,
        const float* __restrict__ g3, const float* __restrict__ b3,
        const float* __restrict__ m3, const float* __restrict__ v3,
        float* __restrict__ out) {
    __shared__ float s_wk[484 * 16];   // [j][px], ~31 KB
    __shared__ float s_t[MID * 16];

    const int tid = threadIdx.x;
    const int p0  = blockIdx.x * 16;   // 16 consecutive px, same image row
    const int px  = tid & 15;
    const int c4  = tid >> 4;          // 0..15

    s_t[tid] = t[c4 * NPIX + p0 + px]; // c4 doubles as mid-channel index
    __syncthreads();

    // phase 2: wk[j][px]; j strided by 16 across c4
    {
        float tr[MID];
        #pragma unroll
        for (int mm = 0; mm < MID; ++mm) tr[mm] = s_t[mm * 16 + px];
        for (int j = c4; j < 484; j += 16) {
            const float4* wrow = (const float4*)(inv_w2 + j * MID);
            float acc = inv_b2[j];
            #pragma unroll
            for (int q = 0; q < 4; ++q) {
                float4 wv = wrow[q];
                acc = fmaf(wv.x, tr[q*4+0], acc);
                acc = fmaf(wv.y, tr[q*4+1], acc);
                acc = fmaf(wv.z, tr[q*4+2], acc);
                acc = fmaf(wv.w, tr[q*4+3], acc);
            }
            s_wk[j * 16 + px] = acc;
        }
    }
    __syncthreads();

    // phase 3: thread = (tx, c), tx = px-quad 0..3, c = channel 0..63.
    // Per (c,kh): one aligned 16-float window covers all 11 kw shifts for
    // 4 output px (padded col = out_col + i + kw, i+kw in [0,13]).
    const int tx = tid & 3;
    const int c  = tid >> 2;
    const int g  = c >> 4;
    const int h  = p0 / WPIX;
    const int wb = (p0 % WPIX) + tx * 4;           // output col base, %4==0
    const float* fbase = feat_pad + c * CHP + h * PADW + wb;
    const float* wkb   = s_wk + (g * KK2) * 16 + tx * 4;

    float acc0 = 0.f, acc1 = 0.f, acc2 = 0.f, acc3 = 0.f;
    #pragma unroll 2
    for (int kh = 0; kh < KK; ++kh) {
        const float4* fp = (const float4*)(fbase + kh * PADW);
        float4 A = fp[0], B = fp[1], Cq = fp[2], D = fp[3];
        float f[16] = {A.x,A.y,A.z,A.w, B.x,B.y,B.z,B.w,
                       Cq.x,Cq.y,Cq.z,Cq.w, D.x,D.y,D.z,D.w};
        const float* wr = wkb + kh * KK * 16;
        #pragma unroll
        for (int kw = 0; kw < KK; ++kw) {
            float4 wv = *(const float4*)(wr + kw * 16);  // wk[j][tx*4..+3]
            acc0 = fmaf(wv.x, f[kw + 0], acc0);
            acc1 = fmaf(wv.y, f[kw + 1], acc1);
            acc2 = fmaf(wv.z, f[kw + 2], acc2);
            acc3 = fmaf(wv.w, f[kw + 3], acc3);
        }
    }

    float inv  = g3[c] * rsqrtf(v3[c] + BN_EPS);
    float beta = b3[c] - m3[c] * inv;
    float4 o;
    o.x = elu_f(fmaf(acc0, inv, beta));
    o.y = elu_f(fmaf(acc1, inv, beta));
    o.z = elu_f(fmaf(acc2, inv, beta));
    o.w = elu_f(fmaf(acc3, inv, beta));
    *(float4*)(out + c * NPIX + p0 + tx * 4) = o;
}

// ---------------- conv3: buf5 -> buf6 (64 -> 128) + fused mean-pool ---------
__global__ __launch_bounds__(256, 4) void k_conv3(
        const float* __restrict__ in, const float* __restrict__ w,
        float* __restrict__ out, float* __restrict__ pooled) {
    const int tid = threadIdx.x;
    const int p   = blockIdx.x * 256 + tid;
    const int oc0 = blockIdx.y * 8;
    const float* wbase = w + oc0 * CM;

    float acc[8] = {0,0,0,0,0,0,0,0};
    #pragma unroll 4
    for (int k = 0; k < CM; ++k) {
        float a = in[k * NPIX + p];
        #pragma unroll
        for (int j = 0; j < 8; ++j)
            acc[j] = fmaf(wbase[j * CM + k], a, acc[j]);
    }
    #pragma unroll
    for (int j = 0; j < 8; ++j)
        out[(oc0 + j) * NPIX + p] = acc[j];

    // fused SE mean-pool partials (sum; /NPIX applied in k_se)
    __shared__ float s_red[8][4];
    const int lane = tid & 63, wid = tid >> 6;
    #pragma unroll
    for (int j = 0; j < 8; ++j) {
        float s = acc[j];
        #pragma unroll
        for (int off = 32; off; off >>= 1) s += __shfl_down(s, off);
        if (lane == 0) s_red[j][wid] = s;
    }
    __syncthreads();
    if (tid < 8) {
        float s = s_red[tid][0] + s_red[tid][1] + s_red[tid][2] + s_red[tid][3];
        atomicAdd(pooled + oc0 + tid, s);
    }
}

// ---------------- SE MLP: 128->8 relu -> 8->128 sigmoid ----------------
__global__ void k_se(const float* __restrict__ pooled,
                     const float* __restrict__ w1, const float* __restrict__ b1,
                     const float* __restrict__ w2, const float* __restrict__ b2,
                     float* __restrict__ scale) {
    __shared__ float s_p[C0];
    __shared__ float s_h[8];
    int tid = threadIdx.x;
    s_p[tid] = pooled[tid] * (1.f / NPIX);
    __syncthreads();
    if (tid < 8) {
        float acc = b1[tid];
        for (int c = 0; c < C0; ++c) acc = fmaf(w1[tid * C0 + c], s_p[c], acc);
        s_h[tid] = fmaxf(acc, 0.f);
    }
    __syncthreads();
    float acc = b2[tid];
    #pragma unroll
    for (int j = 0; j < 8; ++j) acc = fmaf(w2[tid * 8 + j], s_h[j], acc);
    scale[tid] = 1.f / (1.f + expf(-acc));
}

// ---------------- Final: out = pre * scale[c] + x, float4 ----------------
__global__ __launch_bounds__(256) void k_final(
        const float* __restrict__ pre, const float* __restrict__ scale,
        const float* __restrict__ x, float* __restrict__ out) {
    int i4 = blockIdx.x * 256 + threadIdx.x;
    int c = i4 / (NPIX / 4);
    float sc = scale[c];
    float4 pv = ((const float4*)pre)[i4];
    float4 xv = ((const float4*)x)[i4];
    float4 o;
    o.x = fmaf(pv.x, sc, xv.x);
    o.y = fmaf(pv.y, sc, xv.y);
    o.z = fmaf(pv.z, sc, xv.z);
    o.w = fmaf(pv.w, sc, xv.w);
    ((float4*)out)[i4] = o;
}

extern "C" void kernel_launch(void* const* d_in, const int* in_sizes, int n_in,
                              void* d_out, int out_size, void* d_ws, size_t ws_size,
                              hipStream_t stream) {
    const float* x      = (const float*)d_in[0];
    const float* g1     = (const float*)d_in[1];
    const float* b1     = (const float*)d_in[2];
    const float* m1     = (const float*)d_in[3];
    const float* v1     = (const float*)d_in[4];
    const float* w1     = (const float*)d_in[5];
    const float* g2     = (const float*)d_in[6];
    const float* b2     = (const float*)d_in[7];
    const float* m2     = (const float*)d_in[8];
    const float* v2     = (const float*)d_in[9];
    const float* inv_w1 = (const float*)d_in[10];
    const float* ig     = (const float*)d_in[11];
    const float* ib     = (const float*)d_in[12];
    const float* im     = (const float*)d_in[13];
    const float* iv     = (const float*)d_in[14];
    const float* inv_w2 = (const float*)d_in[15];
    const float* inv_b2 = (const float*)d_in[16];
    const float* g3     = (const float*)d_in[17];
    const float* b3     = (const float*)d_in[18];
    const float* m3     = (const float*)d_in[19];
    const float* v3     = (const float*)d_in[20];
    const float* w3     = (const float*)d_in[21];
    const float* se_w1  = (const float*)d_in[22];
    const float* se_b1  = (const float*)d_in[23];
    const float* se_w2  = (const float*)d_in[24];
    const float* se_b2  = (const float*)d_in[25];
    float* out = (float*)d_out;

    float* ws       = (float*)d_ws;
    float* act      = ws;                        // 128*25600 (elu(bn1(x)))
    float* feat_pad = act + C0 * NPIX;           // 64 * 29920 (zero-padded)
    float* buf_t    = feat_pad + CM * CHP;       // 16 * 25600
    float* buf5     = act;                       // alias: act dead after conv1
    float* buf6     = buf_t + MID * NPIX;        // 128 * 25600
    float* pooled   = buf6 + C0 * NPIX;          // 128
    float* scale    = pooled + C0;               // 128

    // zero padded-feat border + pooled accumulators (every call)
    hipMemsetAsync(feat_pad, 0, (size_t)CM * CHP * sizeof(float), stream);
    hipMemsetAsync(pooled, 0, C0 * sizeof(float), stream);

    // 1. act = elu(bn1(x)) once (was recomputed 8x inside conv1)
    k_act<<<(C0 * NPIX / 4) / 256, 256, 0, stream>>>(x, g1, b1, m1, v1, act);

    // 2. conv1x1 128->64 + bn2+elu, into padded layout
    k_conv1<<<dim3(NPIX / 256, CM / 8), 256, 0, stream>>>(
        act, w1, g2, b2, m2, v2, feat_pad);

    // 3a. involution reduce: conv1x1 64->16 + bn + relu
    k_conv_t<<<dim3(NPIX / 256, MID / 2), 256, 0, stream>>>(
        feat_pad, inv_w1, ig, ib, im, iv, buf_t);

    // 3b. involution (wk-gen + weighted patch sum) + bn3 + elu
    k_involution<<<NPIX / 16, 256, 0, stream>>>(buf_t, feat_pad, inv_w2, inv_b2,
                                                g3, b3, m3, v3, buf5);

    // 4. conv1x1 64->128 + fused mean-pool
    k_conv3<<<dim3(NPIX / 256, C0 / 8), 256, 0, stream>>>(buf5, w3, buf6, pooled);

    // 5. SE MLP
    k_se<<<1, C0, 0, stream>>>(pooled, se_w1, se_b1, se_w2, se_b2, scale);

    // 6. out = buf6 * scale + x
    k_final<<<(C0 * NPIX / 4) / 256, 256, 0, stream>>>(buf6, scale, x, out);
}